// Round 7
// baseline (297.072 us; speedup 1.0000x reference)
//
#include <hip/hip_runtime.h>
#include <hip/hip_cooperative_groups.h>
#include <math.h>

namespace cg = cooperative_groups;

#define D_FEAT 128
#define D_DOT  4
#define NBLK   1024   // 4 blocks/CU x 256 CU -> fully co-resident (cooperative)
#define RPB    48     // rows per block per iteration (12 per wave)

// 16 lanes per row (aligned with DPP rows); 12 rows per wave as 3 independent
// groups of 4. DPP row_ror reduction (pure VALU, no LDS). Persistent fused
// kernel: node-projection phase -> grid.sync -> edge phase. W/bias live in
// registers across ALL iterations (prologue paid once per wave).

__device__ __forceinline__ float dot4(const float4 a, const float4 b) {
    return a.x * b.x + a.y * b.y + a.z * b.z + a.w * b.w;
}

template <int CTRL>
__device__ __forceinline__ float dpp_add(float x) {
    union { float f; int i; } u, v;
    u.f = x;
    v.i = __builtin_amdgcn_update_dpp(u.i, u.i, CTRL, 0xF, 0xF, true);
    return x + v.f;
}

__device__ __forceinline__ float row_reduce16(float x) {
    x = dpp_add<0x128>(x);  // row_ror:8
    x = dpp_add<0x124>(x);  // row_ror:4
    x = dpp_add<0x122>(x);  // row_ror:2
    x = dpp_add<0x121>(x);  // row_ror:1
    return x;
}

__global__ __launch_bounds__(256, 4) void fused_kernel(
    const float* __restrict__ n,
    const float* __restrict__ e,
    const float* __restrict__ W,
    const float* __restrict__ bias,
    const int* __restrict__ src_idx,
    const int* __restrict__ dst_idx,
    float* __restrict__ out,
    float* __restrict__ pn,
    int n_nodes, int n_edges)
{
    const int t    = threadIdx.x;
    const int lane = t & 63;
    const int sub  = lane & 15;
    const int g    = lane >> 4;
    const int wave = t >> 6;

    const float4* W4 = reinterpret_cast<const float4*>(W);
    float4 wlo[D_DOT], whi[D_DOT];
#pragma unroll
    for (int k = 0; k < D_DOT; ++k) {
        wlo[k] = W4[k * 32 + sub];
        whi[k] = W4[k * 32 + sub + 16];
    }
    const float b0 = bias[0], b1 = bias[1], b2 = bias[2], b3 = bias[3];

    const int wave_start = blockIdx.x * RPB + wave * 12;
    const int stride = gridDim.x * RPB;

    // ---------------- Phase 1: pn[v] = W . n[v] ----------------
    {
        const int last = n_nodes - 1;
        const float4* n4 = reinterpret_cast<const float4*>(n);
        for (int base = wave_start; base < n_nodes; base += stride) {
            int r[3], c[3];
#pragma unroll
            for (int i = 0; i < 3; ++i) {
                r[i] = base + i * 4 + g;
                c[i] = r[i] > last ? last : r[i];
            }
            float4 xl[3], xh[3];
#pragma unroll
            for (int i = 0; i < 3; ++i) {
                xl[i] = n4[(size_t)c[i] * 32 + sub];
                xh[i] = n4[(size_t)c[i] * 32 + sub + 16];
            }
            float a[3][D_DOT];
#pragma unroll
            for (int i = 0; i < 3; ++i)
#pragma unroll
                for (int k = 0; k < D_DOT; ++k)
                    a[i][k] = dot4(xl[i], wlo[k]) + dot4(xh[i], whi[k]);
#pragma unroll
            for (int i = 0; i < 3; ++i)
#pragma unroll
                for (int k = 0; k < D_DOT; ++k)
                    a[i][k] = row_reduce16(a[i][k]);
#pragma unroll
            for (int i = 0; i < 3; ++i)
                if (sub == 0 && r[i] < n_nodes)
                    reinterpret_cast<float4*>(pn)[r[i]] =
                        make_float4(a[i][0], a[i][1], a[i][2], a[i][3]);
        }
    }

    __threadfence();          // device-scope: make pn visible across XCD L2s
    cg::this_grid().sync();

    // ---------------- Phase 2: per-edge score ----------------
    {
        const int last = n_edges - 1;
        const float4* e4  = reinterpret_cast<const float4*>(e);
        const float4* pn4 = reinterpret_cast<const float4*>(pn);
        for (int base = wave_start; base < n_edges; base += stride) {
            int r[3], c[3];
#pragma unroll
            for (int i = 0; i < 3; ++i) {
                r[i] = base + i * 4 + g;
                c[i] = r[i] > last ? last : r[i];
            }
            int sI[3], dI[3];
#pragma unroll
            for (int i = 0; i < 3; ++i) { sI[i] = src_idx[c[i]]; dI[i] = dst_idx[c[i]]; }

            float4 xl[3], xh[3];
#pragma unroll
            for (int i = 0; i < 3; ++i) {
                xl[i] = e4[(size_t)c[i] * 32 + sub];
                xh[i] = e4[(size_t)c[i] * 32 + sub + 16];
            }
            float4 ps[3], pd[3];
#pragma unroll
            for (int i = 0; i < 3; ++i) { ps[i] = pn4[sI[i]]; pd[i] = pn4[dI[i]]; }

            float a[3][D_DOT];
#pragma unroll
            for (int i = 0; i < 3; ++i)
#pragma unroll
                for (int k = 0; k < D_DOT; ++k)
                    a[i][k] = dot4(xl[i], wlo[k]) + dot4(xh[i], whi[k]);
#pragma unroll
            for (int i = 0; i < 3; ++i)
#pragma unroll
                for (int k = 0; k < D_DOT; ++k)
                    a[i][k] = row_reduce16(a[i][k]);

#pragma unroll
            for (int i = 0; i < 3; ++i) {
                const float u0 = 0.5f * a[i][0] + b0, u1 = 0.5f * a[i][1] + b1;
                const float u2 = 0.5f * a[i][2] + b2, u3 = 0.5f * a[i][3] + b3;
                const float dot = (0.5f * ps[i].x + u0) * (0.5f * pd[i].x + u0)
                                + (0.5f * ps[i].y + u1) * (0.5f * pd[i].y + u1)
                                + (0.5f * ps[i].z + u2) * (0.5f * pd[i].z + u2)
                                + (0.5f * ps[i].w + u3) * (0.5f * pd[i].w + u3);
                if (sub == 0 && r[i] < n_edges)
                    out[r[i]] = 1.0f / (1.0f + __expf(-dot));
            }
        }
    }
}

// ---------------- Fallback path (non-cooperative), proven R6 structure ------
__global__ __launch_bounds__(256, 4) void node_proj_kernel(
    const float* __restrict__ n, const float* __restrict__ W,
    float* __restrict__ pn, int n_nodes)
{
    const int t = threadIdx.x, lane = t & 63, sub = lane & 15, g = lane >> 4;
    const int wave = t >> 6;
    const int base = blockIdx.x * RPB + wave * 12;
    const int last = n_nodes - 1;
    int r[3], c[3];
#pragma unroll
    for (int i = 0; i < 3; ++i) { r[i] = base + i * 4 + g; c[i] = r[i] > last ? last : r[i]; }
    const float4* n4 = reinterpret_cast<const float4*>(n);
    float4 xl[3], xh[3];
#pragma unroll
    for (int i = 0; i < 3; ++i) {
        xl[i] = n4[(size_t)c[i] * 32 + sub];
        xh[i] = n4[(size_t)c[i] * 32 + sub + 16];
    }
    const float4* W4 = reinterpret_cast<const float4*>(W);
    float4 wlo[D_DOT], whi[D_DOT];
#pragma unroll
    for (int k = 0; k < D_DOT; ++k) { wlo[k] = W4[k * 32 + sub]; whi[k] = W4[k * 32 + sub + 16]; }
    float a[3][D_DOT];
#pragma unroll
    for (int i = 0; i < 3; ++i)
#pragma unroll
        for (int k = 0; k < D_DOT; ++k)
            a[i][k] = dot4(xl[i], wlo[k]) + dot4(xh[i], whi[k]);
#pragma unroll
    for (int i = 0; i < 3; ++i)
#pragma unroll
        for (int k = 0; k < D_DOT; ++k)
            a[i][k] = row_reduce16(a[i][k]);
#pragma unroll
    for (int i = 0; i < 3; ++i)
        if (sub == 0 && r[i] < n_nodes)
            reinterpret_cast<float4*>(pn)[r[i]] = make_float4(a[i][0], a[i][1], a[i][2], a[i][3]);
}

__global__ __launch_bounds__(256, 4) void edge_score_kernel(
    const float* __restrict__ e, const float* __restrict__ W,
    const float* __restrict__ bias, const float* __restrict__ pn,
    const int* __restrict__ src_idx, const int* __restrict__ dst_idx,
    float* __restrict__ out, int n_edges)
{
    const int t = threadIdx.x, lane = t & 63, sub = lane & 15, g = lane >> 4;
    const int wave = t >> 6;
    const int base = blockIdx.x * RPB + wave * 12;
    const int last = n_edges - 1;
    int r[3], c[3];
#pragma unroll
    for (int i = 0; i < 3; ++i) { r[i] = base + i * 4 + g; c[i] = r[i] > last ? last : r[i]; }
    int sI[3], dI[3];
#pragma unroll
    for (int i = 0; i < 3; ++i) { sI[i] = src_idx[c[i]]; dI[i] = dst_idx[c[i]]; }
    const float4* e4 = reinterpret_cast<const float4*>(e);
    float4 xl[3], xh[3];
#pragma unroll
    for (int i = 0; i < 3; ++i) {
        xl[i] = e4[(size_t)c[i] * 32 + sub];
        xh[i] = e4[(size_t)c[i] * 32 + sub + 16];
    }
    const float4* W4 = reinterpret_cast<const float4*>(W);
    float4 wlo[D_DOT], whi[D_DOT];
#pragma unroll
    for (int k = 0; k < D_DOT; ++k) { wlo[k] = W4[k * 32 + sub]; whi[k] = W4[k * 32 + sub + 16]; }
    const float b0 = bias[0], b1 = bias[1], b2 = bias[2], b3 = bias[3];
    const float4* pn4 = reinterpret_cast<const float4*>(pn);
    float4 ps[3], pd[3];
#pragma unroll
    for (int i = 0; i < 3; ++i) { ps[i] = pn4[sI[i]]; pd[i] = pn4[dI[i]]; }
    float a[3][D_DOT];
#pragma unroll
    for (int i = 0; i < 3; ++i)
#pragma unroll
        for (int k = 0; k < D_DOT; ++k)
            a[i][k] = dot4(xl[i], wlo[k]) + dot4(xh[i], whi[k]);
#pragma unroll
    for (int i = 0; i < 3; ++i)
#pragma unroll
        for (int k = 0; k < D_DOT; ++k)
            a[i][k] = row_reduce16(a[i][k]);
#pragma unroll
    for (int i = 0; i < 3; ++i) {
        const float u0 = 0.5f * a[i][0] + b0, u1 = 0.5f * a[i][1] + b1;
        const float u2 = 0.5f * a[i][2] + b2, u3 = 0.5f * a[i][3] + b3;
        const float dot = (0.5f * ps[i].x + u0) * (0.5f * pd[i].x + u0)
                        + (0.5f * ps[i].y + u1) * (0.5f * pd[i].y + u1)
                        + (0.5f * ps[i].z + u2) * (0.5f * pd[i].z + u2)
                        + (0.5f * ps[i].w + u3) * (0.5f * pd[i].w + u3);
        if (sub == 0 && r[i] < n_edges)
            out[r[i]] = 1.0f / (1.0f + __expf(-dot));
    }
}

extern "C" void kernel_launch(void* const* d_in, const int* in_sizes, int n_in,
                              void* d_out, int out_size, void* d_ws, size_t ws_size,
                              hipStream_t stream) {
    const float* n    = (const float*)d_in[0];
    const float* e    = (const float*)d_in[1];
    const float* W    = (const float*)d_in[2];
    const float* bias = (const float*)d_in[3];
    const int*   src  = (const int*)d_in[4];
    const int*   dst  = (const int*)d_in[5];
    float* out = (float*)d_out;

    int n_nodes = in_sizes[0] / D_FEAT;
    int n_edges = in_sizes[1] / D_FEAT;

    float* pn = (float*)d_ws;  // n_nodes * 4 floats

    void* args[] = {(void*)&n, (void*)&e, (void*)&W, (void*)&bias,
                    (void*)&src, (void*)&dst, (void*)&out, (void*)&pn,
                    (void*)&n_nodes, (void*)&n_edges};
    hipError_t err = hipLaunchCooperativeKernel((const void*)fused_kernel,
                                                dim3(NBLK), dim3(256),
                                                args, 0, stream);
    if (err != hipSuccess) {
        // deterministic fallback: proven two-kernel path
        const int nblk = (n_nodes + RPB - 1) / RPB;
        const int eblk = (n_edges + RPB - 1) / RPB;
        node_proj_kernel<<<nblk, 256, 0, stream>>>(n, W, pn, n_nodes);
        edge_score_kernel<<<eblk, 256, 0, stream>>>(e, W, bias, pn, src, dst, out, n_edges);
    }
}

// Round 9
// 73.183 us; speedup vs baseline: 4.0593x; 4.0593x over previous
//
#include <hip/hip_runtime.h>
#include <math.h>

#define D_FEAT 128
#define D_DOT  4

// Two-kernel structure (cooperative fusion regressed 4x in R7 — reverted).
// 16 lanes per row (aligned to DPP rows); 16 rows per wave as 4 independent
// groups of 4 (U=4). DPP row_ror reduction (pure VALU, no LDS pipe).
// e/n row streams use non-temporal loads (no reuse); pn stays L2-cached.
// pn holds 0.5 * (W . n) so the edge epilogue is hs = ps + (0.5*pe + b).

typedef float vfloat4 __attribute__((ext_vector_type(4)));  // native vec for nt-load

__device__ __forceinline__ float dot4v(const vfloat4 a, const float4 b) {
    return a.x * b.x + a.y * b.y + a.z * b.z + a.w * b.w;
}

__device__ __forceinline__ vfloat4 ntload4(const float* p) {
    return __builtin_nontemporal_load(reinterpret_cast<const vfloat4*>(p));
}

template <int CTRL>
__device__ __forceinline__ float dpp_add(float x) {
    union { float f; int i; } u, v;
    u.f = x;
    v.i = __builtin_amdgcn_update_dpp(u.i, u.i, CTRL, 0xF, 0xF, true);
    return x + v.f;
}

__device__ __forceinline__ float row_reduce16(float x) {
    x = dpp_add<0x128>(x);  // row_ror:8
    x = dpp_add<0x124>(x);  // row_ror:4
    x = dpp_add<0x122>(x);  // row_ror:2
    x = dpp_add<0x121>(x);  // row_ror:1
    return x;
}

#define U 4   // row-groups per wave; 16 rows/wave, 64 rows/block

__global__ __launch_bounds__(256, 4) void node_proj_kernel(
    const float* __restrict__ n,
    const float* __restrict__ W,
    float* __restrict__ pn,
    int n_nodes)
{
    const int t    = threadIdx.x;
    const int lane = t & 63;
    const int sub  = lane & 15;
    const int g    = lane >> 4;
    const int wave = t >> 6;
    const int base = blockIdx.x * (U * 16) + wave * (U * 4);
    const int last = n_nodes - 1;

    int r[U], c[U];
#pragma unroll
    for (int i = 0; i < U; ++i) {
        r[i] = base + i * 4 + g;
        c[i] = r[i] > last ? last : r[i];
    }

    vfloat4 xl[U], xh[U];
#pragma unroll
    for (int i = 0; i < U; ++i) {
        xl[i] = ntload4(&n[(size_t)c[i] * D_FEAT + sub * 4]);
        xh[i] = ntload4(&n[(size_t)c[i] * D_FEAT + 64 + sub * 4]);
    }

    const float4* W4 = reinterpret_cast<const float4*>(W);
    float4 wlo[D_DOT], whi[D_DOT];
#pragma unroll
    for (int k = 0; k < D_DOT; ++k) {
        wlo[k] = W4[k * 32 + sub];
        whi[k] = W4[k * 32 + sub + 16];
    }

    float a[U][D_DOT];
#pragma unroll
    for (int i = 0; i < U; ++i)
#pragma unroll
        for (int k = 0; k < D_DOT; ++k)
            a[i][k] = dot4v(xl[i], wlo[k]) + dot4v(xh[i], whi[k]);

#pragma unroll
    for (int i = 0; i < U; ++i)
#pragma unroll
        for (int k = 0; k < D_DOT; ++k)
            a[i][k] = row_reduce16(a[i][k]);

#pragma unroll
    for (int i = 0; i < U; ++i)
        if (sub == 0 && r[i] < n_nodes)
            reinterpret_cast<float4*>(pn)[r[i]] =
                make_float4(0.5f * a[i][0], 0.5f * a[i][1],
                            0.5f * a[i][2], 0.5f * a[i][3]);
}

__global__ __launch_bounds__(256, 3) void edge_score_kernel(
    const float* __restrict__ e,
    const float* __restrict__ W,
    const float* __restrict__ bias,
    const float* __restrict__ pn,
    const int* __restrict__ src_idx,
    const int* __restrict__ dst_idx,
    float* __restrict__ out,
    int n_edges)
{
    const int t    = threadIdx.x;
    const int lane = t & 63;
    const int sub  = lane & 15;
    const int g    = lane >> 4;
    const int wave = t >> 6;
    const int base = blockIdx.x * (U * 16) + wave * (U * 4);
    const int last = n_edges - 1;

    int r[U], c[U];
#pragma unroll
    for (int i = 0; i < U; ++i) {
        r[i] = base + i * 4 + g;
        c[i] = r[i] > last ? last : r[i];
    }

    // 1) idx loads (small, enable the pn gathers)
    int sI[U], dI[U];
#pragma unroll
    for (int i = 0; i < U; ++i) { sI[i] = src_idx[c[i]]; dI[i] = dst_idx[c[i]]; }

    // 2) bulk row stream (non-temporal; longest latency, most bytes)
    vfloat4 xl[U], xh[U];
#pragma unroll
    for (int i = 0; i < U; ++i) {
        xl[i] = ntload4(&e[(size_t)c[i] * D_FEAT + sub * 4]);
        xh[i] = ntload4(&e[(size_t)c[i] * D_FEAT + 64 + sub * 4]);
    }

    // 3) pn gathers (chain off idx; overlap the FMA work below)
    const float4* pn4 = reinterpret_cast<const float4*>(pn);
    float4 ps[U], pd[U];
#pragma unroll
    for (int i = 0; i < U; ++i) { ps[i] = pn4[sI[i]]; pd[i] = pn4[dI[i]]; }

    const float4* W4 = reinterpret_cast<const float4*>(W);
    float4 wlo[D_DOT], whi[D_DOT];
#pragma unroll
    for (int k = 0; k < D_DOT; ++k) {
        wlo[k] = W4[k * 32 + sub];
        whi[k] = W4[k * 32 + sub + 16];
    }
    const float b0 = bias[0], b1 = bias[1], b2 = bias[2], b3 = bias[3];

    float a[U][D_DOT];
#pragma unroll
    for (int i = 0; i < U; ++i)
#pragma unroll
        for (int k = 0; k < D_DOT; ++k)
            a[i][k] = dot4v(xl[i], wlo[k]) + dot4v(xh[i], whi[k]);

#pragma unroll
    for (int i = 0; i < U; ++i)
#pragma unroll
        for (int k = 0; k < D_DOT; ++k)
            a[i][k] = row_reduce16(a[i][k]);

#pragma unroll
    for (int i = 0; i < U; ++i) {
        const float u0 = 0.5f * a[i][0] + b0, u1 = 0.5f * a[i][1] + b1;
        const float u2 = 0.5f * a[i][2] + b2, u3 = 0.5f * a[i][3] + b3;
        const float dot = (ps[i].x + u0) * (pd[i].x + u0)
                        + (ps[i].y + u1) * (pd[i].y + u1)
                        + (ps[i].z + u2) * (pd[i].z + u2)
                        + (ps[i].w + u3) * (pd[i].w + u3);
        if (sub == 0 && r[i] < n_edges)
            out[r[i]] = 1.0f / (1.0f + __expf(-dot));
    }
}

extern "C" void kernel_launch(void* const* d_in, const int* in_sizes, int n_in,
                              void* d_out, int out_size, void* d_ws, size_t ws_size,
                              hipStream_t stream) {
    const float* n    = (const float*)d_in[0];
    const float* e    = (const float*)d_in[1];
    const float* W    = (const float*)d_in[2];
    const float* bias = (const float*)d_in[3];
    const int*   src  = (const int*)d_in[4];
    const int*   dst  = (const int*)d_in[5];
    float* out = (float*)d_out;

    const int n_nodes = in_sizes[0] / D_FEAT;
    const int n_edges = in_sizes[1] / D_FEAT;

    float* pn = (float*)d_ws;  // n_nodes * 4 floats (holds 0.5 * W.n)

    const int nblk = (n_nodes + 63) / 64;
    const int eblk = (n_edges + 63) / 64;   // 600000 / 64 = 9375 exact
    node_proj_kernel<<<nblk, 256, 0, stream>>>(n, W, pn, n_nodes);
    edge_score_kernel<<<eblk, 256, 0, stream>>>(e, W, bias, pn, src, dst, out, n_edges);
}

// Round 10
// 70.804 us; speedup vs baseline: 4.1957x; 1.0336x over previous
//
#include <hip/hip_runtime.h>
#include <math.h>

#define D_FEAT 128
#define D_DOT  4
#define U      4    // row-groups per wave; 16 rows/wave, 64 rows/block

// R10 structure:
//  Kernel A (merged stream, one launch, blockIdx-partitioned, no sync needed):
//    edge-blocks:  q[edge] = 0.5*(W . e[edge]) + b     (pure stream)
//    node-blocks:  pn[v]   = 0.5*(W . n[v])            (pure stream)
//  Kernel B (epilogue, one edge per lane):
//    out = sigmoid( sum_k (pn[src]+q)_k * (pn[dst]+q)_k )
// 16 lanes per row aligned to DPP rows; DPP row_ror reduce (pure VALU).
// Row streams are non-temporal (zero reuse); pn/q stay normally cached.

typedef float vfloat4 __attribute__((ext_vector_type(4)));

__device__ __forceinline__ float dot4v(const vfloat4 a, const float4 b) {
    return a.x * b.x + a.y * b.y + a.z * b.z + a.w * b.w;
}

__device__ __forceinline__ vfloat4 ntload4(const float* p) {
    return __builtin_nontemporal_load(reinterpret_cast<const vfloat4*>(p));
}

template <int CTRL>
__device__ __forceinline__ float dpp_add(float x) {
    union { float f; int i; } u, v;
    u.f = x;
    v.i = __builtin_amdgcn_update_dpp(u.i, u.i, CTRL, 0xF, 0xF, true);
    return x + v.f;
}

__device__ __forceinline__ float row_reduce16(float x) {
    x = dpp_add<0x128>(x);  // row_ror:8
    x = dpp_add<0x124>(x);  // row_ror:4
    x = dpp_add<0x122>(x);  // row_ror:2
    x = dpp_add<0x121>(x);  // row_ror:1
    return x;
}

// Project 16 rows/wave of src (row-major, 128 floats/row) through W; result
// scaled by 0.5, plus (bias0..3 or 0). Store float4 per row from sub==0.
__device__ __forceinline__ void project_rows(
    const float* __restrict__ src, float4* __restrict__ dst4,
    const float* __restrict__ W, int n_rows, int block_i,
    float ab0, float ab1, float ab2, float ab3)
{
    const int t    = threadIdx.x;
    const int lane = t & 63;
    const int sub  = lane & 15;
    const int g    = lane >> 4;
    const int wave = t >> 6;
    const int base = block_i * (U * 16) + wave * (U * 4);
    const int last = n_rows - 1;

    int r[U], c[U];
#pragma unroll
    for (int i = 0; i < U; ++i) {
        r[i] = base + i * 4 + g;
        c[i] = r[i] > last ? last : r[i];
    }

    vfloat4 xl[U], xh[U];
#pragma unroll
    for (int i = 0; i < U; ++i) {
        xl[i] = ntload4(&src[(size_t)c[i] * D_FEAT + sub * 4]);
        xh[i] = ntload4(&src[(size_t)c[i] * D_FEAT + 64 + sub * 4]);
    }

    const float4* W4 = reinterpret_cast<const float4*>(W);
    float4 wlo[D_DOT], whi[D_DOT];
#pragma unroll
    for (int k = 0; k < D_DOT; ++k) {
        wlo[k] = W4[k * 32 + sub];
        whi[k] = W4[k * 32 + sub + 16];
    }

    float a[U][D_DOT];
#pragma unroll
    for (int i = 0; i < U; ++i)
#pragma unroll
        for (int k = 0; k < D_DOT; ++k)
            a[i][k] = dot4v(xl[i], wlo[k]) + dot4v(xh[i], whi[k]);

#pragma unroll
    for (int i = 0; i < U; ++i)
#pragma unroll
        for (int k = 0; k < D_DOT; ++k)
            a[i][k] = row_reduce16(a[i][k]);

#pragma unroll
    for (int i = 0; i < U; ++i)
        if (sub == 0 && r[i] < n_rows)
            dst4[r[i]] = make_float4(0.5f * a[i][0] + ab0, 0.5f * a[i][1] + ab1,
                                     0.5f * a[i][2] + ab2, 0.5f * a[i][3] + ab3);
}

__global__ __launch_bounds__(256, 4) void stream_proj_kernel(
    const float* __restrict__ e,
    const float* __restrict__ n,
    const float* __restrict__ W,
    const float* __restrict__ bias,
    float* __restrict__ q,    // [n_edges][4]  = 0.5*(W.e)+b
    float* __restrict__ pn,   // [n_nodes][4]  = 0.5*(W.n)
    int n_edges, int n_nodes, int eblk)
{
    if ((int)blockIdx.x < eblk) {
        const float b0 = bias[0], b1 = bias[1], b2 = bias[2], b3 = bias[3];
        project_rows(e, reinterpret_cast<float4*>(q), W, n_edges, blockIdx.x,
                     b0, b1, b2, b3);
    } else {
        project_rows(n, reinterpret_cast<float4*>(pn), W, n_nodes,
                     blockIdx.x - eblk, 0.f, 0.f, 0.f, 0.f);
    }
}

__global__ __launch_bounds__(256, 8) void edge_epilogue_kernel(
    const float* __restrict__ q,
    const float* __restrict__ pn,
    const int* __restrict__ src_idx,
    const int* __restrict__ dst_idx,
    float* __restrict__ out,
    int n_edges)
{
    const int tid = blockIdx.x * 256 + threadIdx.x;
    if (tid >= n_edges) return;

    const int s = src_idx[tid];
    const int d = dst_idx[tid];
    const float4 qe = reinterpret_cast<const float4*>(q)[tid];
    const float4 ps = reinterpret_cast<const float4*>(pn)[s];
    const float4 pd = reinterpret_cast<const float4*>(pn)[d];

    const float dot = (ps.x + qe.x) * (pd.x + qe.x)
                    + (ps.y + qe.y) * (pd.y + qe.y)
                    + (ps.z + qe.z) * (pd.z + qe.z)
                    + (ps.w + qe.w) * (pd.w + qe.w);
    out[tid] = 1.0f / (1.0f + __expf(-dot));
}

extern "C" void kernel_launch(void* const* d_in, const int* in_sizes, int n_in,
                              void* d_out, int out_size, void* d_ws, size_t ws_size,
                              hipStream_t stream) {
    const float* n    = (const float*)d_in[0];
    const float* e    = (const float*)d_in[1];
    const float* W    = (const float*)d_in[2];
    const float* bias = (const float*)d_in[3];
    const int*   src  = (const int*)d_in[4];
    const int*   dst  = (const int*)d_in[5];
    float* out = (float*)d_out;

    const int n_nodes = in_sizes[0] / D_FEAT;
    const int n_edges = in_sizes[1] / D_FEAT;

    // workspace layout: pn [n_nodes*4] | q [n_edges*4]
    float* pn = (float*)d_ws;
    float* q  = pn + (size_t)n_nodes * D_DOT;

    const int eblk = (n_edges + 63) / 64;   // 600000/64 = 9375 exact
    const int nblk = (n_nodes + 63) / 64;
    stream_proj_kernel<<<eblk + nblk, 256, 0, stream>>>(
        e, n, W, bias, q, pn, n_edges, n_nodes, eblk);

    const int pblk = (n_edges + 255) / 256;
    edge_epilogue_kernel<<<pblk, 256, 0, stream>>>(q, pn, src, dst, out, n_edges);
}